// Round 18
// baseline (92.633 us; speedup 1.0000x reference)
//
#include <hip/hip_runtime.h>
#include <stdint.h>

#define SEQ 2048
#define DM 1024
#define NH 16
#define DH 64
#define LN_EPS 1e-5f

typedef __bf16 bf16x8 __attribute__((ext_vector_type(8)));
typedef float f32x4 __attribute__((ext_vector_type(4)));
typedef unsigned short u16;
typedef unsigned short u16x8 __attribute__((ext_vector_type(8)));
typedef unsigned int u32;
typedef short s16x4 __attribute__((ext_vector_type(4)));

__device__ __forceinline__ u16 f2bf(float f) {
  unsigned int u = __float_as_uint(f);
  unsigned int r = (u + 0x7fffu + ((u >> 16) & 1u)) >> 16;
  return (u16)r;
}

__device__ __forceinline__ float bf2f(u16 x) {
  return __uint_as_float(((u32)x) << 16);
}

__device__ __forceinline__ u32 packbf(float a, float b) {
  union { __bf16 h[2]; u32 u; } pw;
  pw.h[0] = (__bf16)a; pw.h[1] = (__bf16)b;
  return pw.u;
}

// raw v_exp_f32 (2^x). Args are bounded (|x|<40) so no OCML range fixup needed.
__device__ __forceinline__ float fast_exp2(float x) {
#if __has_builtin(__builtin_amdgcn_exp2f)
  return __builtin_amdgcn_exp2f(x);
#else
  float r;
  asm("v_exp_f32 %0, %1" : "=v"(r) : "v"(x));
  return r;
#endif
}

// 16x16x16 bf16 MFMA (2-reg A/B).
__device__ __forceinline__ f32x4 mfma16x16x16bf(s16x4 a, s16x4 b, f32x4 c) {
#if __has_builtin(__builtin_amdgcn_mfma_f32_16x16x16bf16_1k)
  return __builtin_amdgcn_mfma_f32_16x16x16bf16_1k(a, b, c, 0, 0, 0);
#else
  asm("v_mfma_f32_16x16x16_bf16 %0, %1, %2, %0" : "+v"(c) : "v"(a), "v"(b));
  return c;
#endif
}

#define GLD_LDS16(gp, lp) __builtin_amdgcn_global_load_lds( \
  (const __attribute__((address_space(1))) void*)(gp),      \
  (__attribute__((address_space(3))) void*)(lp), 16, 0, 0)

// ---------------- fused f32 -> bf16 convert (h, Wqkv, Wout in one launch) ----
__global__ __launch_bounds__(256)
void k_f2bf3(const float* __restrict__ a, u16* __restrict__ oa, int na,
             const float* __restrict__ b, u16* __restrict__ ob, int nb,
             const float* __restrict__ c, u16* __restrict__ oc, int nc) {
  int i = blockIdx.x * 256 + threadIdx.x;
  const float* src;
  u16* dst;
  if (i < na) { src = a; dst = oa; }
  else if (i < na + nb) { src = b; dst = ob; i -= na; }
  else if (i < na + nb + nc) { src = c; dst = oc; i -= na + nb; }
  else return;
  float4 v = reinterpret_cast<const float4*>(src)[i];
  ushort4 o;
  o.x = f2bf(v.x); o.y = f2bf(v.y); o.z = f2bf(v.z); o.w = f2bf(v.w);
  reinterpret_cast<ushort4*>(dst)[i] = o;
}

// ---------------- GEMM: C = A(bf16 MxK) * B(bf16 NxK)^T (QKV) ----------------
// BK=64, swizzled LDS, counted-vmcnt pipeline (round-17 best).
// EPI 2: QKV split: n<2048 -> outb[m][n]; n>=2048 -> outv[(n-2048)][m] (V^T).
template <int EPI, int BM, int BN, int XCDW>
__global__ __launch_bounds__(256)
void k_gemm_bt(const u16* __restrict__ A, const u16* __restrict__ B,
               const float* __restrict__ bias,
               u16* __restrict__ outb, u16* __restrict__ outv,
               int M, int N, int K) {
  constexpr int MF = BM / 32, NF = BN / 32;
  constexpr int WM = BM / 2, WN = BN / 2;
  constexpr int NLOAD = BM / 32 + BN / 32;
  __shared__ u16 Alds[2][BM][64];
  __shared__ u16 Blds[2][BN][64];
  const int tid = threadIdx.x;
  const int w = tid >> 6, l = tid & 63, lg = l >> 4, lr = l & 15;
  const int wr = w >> 1, wc = w & 1;

  int bx = blockIdx.x, by = blockIdx.y, bz = blockIdx.z;
  if (XCDW > 0) {
    const int nx = gridDim.x, ny = gridDim.y;
    const int u = bx + nx * (by + ny * bz);
    const int xcd = u & 7, g = u >> 3;
    bx = xcd * XCDW + (g % XCDW);
    const int rem = g / XCDW;
    by = rem % ny;
    bz = rem / ny;
  }

  const int m0 = by * BM, n0 = bx * BN;
  const int KTall = K >> 6;
  const int ktn = KTall / gridDim.z;
  const int kt0 = bz * ktn;

  f32x4 acc[MF][NF] = {};

  const int srow = l >> 3;
  const int scol = ((l & 7) ^ (srow & 7)) * 8;
  auto stage = [&](int buf, int kt) {
    const int k0 = kt << 6;
#pragma unroll
    for (int p = 0; p < BM / 32; ++p) {
      const int rbase = (w * (BM / 32) + p) * 8;
      GLD_LDS16(A + (size_t)(m0 + rbase + srow) * K + k0 + scol, &Alds[buf][rbase][0]);
    }
#pragma unroll
    for (int p = 0; p < BN / 32; ++p) {
      const int rbase = (w * (BN / 32) + p) * 8;
      GLD_LDS16(B + (size_t)(n0 + rbase + srow) * K + k0 + scol, &Blds[buf][rbase][0]);
    }
  };

  auto aread = [&](int buf, int row, int kbyte) -> bf16x8 {
    const int off = row * 128 + (kbyte ^ ((row & 7) << 4));
    return *reinterpret_cast<const bf16x8*>(
        reinterpret_cast<const char*>(&Alds[buf][0][0]) + off);
  };
  auto bread = [&](int buf, int row, int kbyte) -> bf16x8 {
    const int off = row * 128 + (kbyte ^ ((row & 7) << 4));
    return *reinterpret_cast<const bf16x8*>(
        reinterpret_cast<const char*>(&Blds[buf][0][0]) + off);
  };

  auto compute = [&](int buf) {
#pragma unroll
    for (int kk = 0; kk < 2; ++kk) {
      bf16x8 af[MF], bfr[NF];
#pragma unroll
      for (int mi = 0; mi < MF; ++mi)
        af[mi] = aread(buf, wr * WM + mi * 16 + lr, kk * 64 + lg * 16);
#pragma unroll
      for (int ni = 0; ni < NF; ++ni)
        bfr[ni] = bread(buf, wc * WN + ni * 16 + lr, kk * 64 + lg * 16);
#pragma unroll
      for (int mi = 0; mi < MF; ++mi)
#pragma unroll
        for (int ni = 0; ni < NF; ++ni)
          acc[mi][ni] = __builtin_amdgcn_mfma_f32_16x16x32_bf16(af[mi], bfr[ni], acc[mi][ni], 0, 0, 0);
    }
  };

  stage(0, kt0);
  for (int i = 0; i < ktn; ++i) {
    const int cur = i & 1;
    if (i + 1 < ktn) {
      stage(cur ^ 1, kt0 + i + 1);
      if (NLOAD == 6)      asm volatile("s_waitcnt vmcnt(6)" ::: "memory");
      else if (NLOAD == 4) asm volatile("s_waitcnt vmcnt(4)" ::: "memory");
      else                 asm volatile("s_waitcnt vmcnt(0)" ::: "memory");
    } else {
      asm volatile("s_waitcnt vmcnt(0)" ::: "memory");
    }
    __builtin_amdgcn_s_barrier();
    compute(cur);
    __builtin_amdgcn_s_barrier();
  }

  // EPI == 2
  if (n0 < 2048) {
#pragma unroll
    for (int ni = 0; ni < NF; ++ni) {
      const int n = n0 + wc * WN + ni * 16 + lr;
      const float bn = bias[n];
#pragma unroll
      for (int mi = 0; mi < MF; ++mi) {
#pragma unroll
        for (int r = 0; r < 4; ++r) {
          const int m = m0 + wr * WM + mi * 16 + lg * 4 + r;
          outb[(size_t)m * 2048 + n] = f2bf(acc[mi][ni][r] + bn);
        }
      }
    }
  } else {
#pragma unroll
    for (int ni = 0; ni < NF; ++ni) {
      const int n = n0 + wc * WN + ni * 16 + lr;
      const float bn = bias[n];
#pragma unroll
      for (int mi = 0; mi < MF; ++mi) {
        const int mb = m0 + wr * WM + mi * 16 + lg * 4;
        ushort4 pk;
        pk.x = f2bf(acc[mi][ni][0] + bn);
        pk.y = f2bf(acc[mi][ni][1] + bn);
        pk.z = f2bf(acc[mi][ni][2] + bn);
        pk.w = f2bf(acc[mi][ni][3] + bn);
        *reinterpret_cast<ushort4*>(&outv[(size_t)(n - 2048) * M + mb]) = pk;
      }
    }
  }
}

// ---------------- fused out-proj: combine KV-splits in A-staging ------------
// A[m][k] = (sum_s Opart[s][m][k]) * inv_den[m][h=k/64]; head == k-tile since
// DH == BK == 64. inv_den precomputed into LDS once per block. A reg-staged
// (linear global read, swizzled ds_write); B (W_out) via global_load_lds.
// Writes bf16 partials outp[z][m][n] (split-K=2), summed in k_ln.
__global__ __launch_bounds__(256)
void k_outproj(const u16* __restrict__ Opart, const float* __restrict__ lsums,
               const u16* __restrict__ B, u16* __restrict__ outp,
               int M, int N, int K) {
  constexpr int BM = 64, BN = 64, MF = 2, NF = 2, WM = 32, WN = 32;
  __shared__ u16 Alds[2][BM][64];
  __shared__ u16 Blds[2][BN][64];
  __shared__ float invden[64 * 16];
  const int tid = threadIdx.x;
  const int w = tid >> 6, l = tid & 63, lg = l >> 4, lr = l & 15;
  const int wr = w >> 1, wc = w & 1;

  int bx = blockIdx.x, by = blockIdx.y, bz = blockIdx.z;
  {
    const int nx = gridDim.x, ny = gridDim.y;
    const int u = bx + nx * (by + ny * bz);
    const int xcd = u & 7, g = u >> 3;
    bx = xcd * 2 + (g % 2);
    const int rem = g / 2;
    by = rem % ny;
    bz = rem / ny;
  }
  const int m0 = by * BM, n0 = bx * BN;
  const int ktn = (K >> 6) / gridDim.z;   // 8
  const int kt0 = bz * ktn;

  // precompute 1/den for this block's 64 rows x 16 heads (4 entries/thread)
#pragma unroll
  for (int j = 0; j < 4; ++j) {
    const int v = tid * 4 + j;
    const int row = v >> 4, hh = v & 15;
    float den = 0.f;
#pragma unroll
    for (int s = 0; s < 4; ++s)
      den += lsums[(size_t)(s * 16 + hh) * SEQ + m0 + row];
    invden[row * 16 + hh] = 1.f / den;
  }
  __syncthreads();

  f32x4 acc[MF][NF] = {};

  const int srow = l >> 3;                 // 0..7
  const int c8 = l & 7;                    // A col chunk (linear)
  const int scolB = ((l & 7) ^ (srow & 7)) * 8;
  u16x8 areg[2][4];

  // stage: issue A global loads (8) + B dma (2); vmcnt(2) -> A regs ready
  // (also implies previous tile's B dma completed); combine + swizzled write.
  auto stage = [&](int buf, int kt) {
#pragma unroll
    for (int p = 0; p < 2; ++p) {
      const int row = (w * 2 + p) * 8 + srow;
      const u16* src = Opart + (size_t)(m0 + row) * 1024 + kt * 64 + c8 * 8;
#pragma unroll
      for (int s = 0; s < 4; ++s)
        areg[p][s] = *reinterpret_cast<const u16x8*>(src + (size_t)s * SEQ * 1024);
    }
#pragma unroll
    for (int p = 0; p < 2; ++p) {
      const int rbase = (w * 2 + p) * 8;
      GLD_LDS16(B + (size_t)(n0 + rbase + srow) * K + (kt << 6) + scolB,
                &Blds[buf][rbase][0]);
    }
    asm volatile("s_waitcnt vmcnt(2)" ::: "memory");
#pragma unroll
    for (int p = 0; p < 2; ++p) {
      const int row = (w * 2 + p) * 8 + srow;
      const float inv = invden[row * 16 + kt];
      u16x8 pk;
#pragma unroll
      for (int j = 0; j < 8; ++j) {
        const float o = bf2f((u16)areg[p][0][j]) + bf2f((u16)areg[p][1][j]) +
                        bf2f((u16)areg[p][2][j]) + bf2f((u16)areg[p][3][j]);
        pk[j] = f2bf(o * inv);
      }
      char* dst = reinterpret_cast<char*>(&Alds[buf][0][0]) + row * 128 +
                  ((c8 * 16) ^ ((row & 7) << 4));
      *reinterpret_cast<u16x8*>(dst) = pk;
    }
  };

  auto aread = [&](int buf, int row, int kbyte) -> bf16x8 {
    const int off = row * 128 + (kbyte ^ ((row & 7) << 4));
    return *reinterpret_cast<const bf16x8*>(
        reinterpret_cast<const char*>(&Alds[buf][0][0]) + off);
  };
  auto bread = [&](int buf, int row, int kbyte) -> bf16x8 {
    const int off = row * 128 + (kbyte ^ ((row & 7) << 4));
    return *reinterpret_cast<const bf16x8*>(
        reinterpret_cast<const char*>(&Blds[buf][0][0]) + off);
  };

  auto compute = [&](int buf) {
#pragma unroll
    for (int kk = 0; kk < 2; ++kk) {
      bf16x8 af[MF], bfr[NF];
#pragma unroll
      for (int mi = 0; mi < MF; ++mi)
        af[mi] = aread(buf, wr * WM + mi * 16 + lr, kk * 64 + lg * 16);
#pragma unroll
      for (int ni = 0; ni < NF; ++ni)
        bfr[ni] = bread(buf, wc * WN + ni * 16 + lr, kk * 64 + lg * 16);
#pragma unroll
      for (int mi = 0; mi < MF; ++mi)
#pragma unroll
        for (int ni = 0; ni < NF; ++ni)
          acc[mi][ni] = __builtin_amdgcn_mfma_f32_16x16x32_bf16(af[mi], bfr[ni], acc[mi][ni], 0, 0, 0);
    }
  };

  stage(0, kt0);
  for (int i = 0; i < ktn; ++i) {
    const int cur = i & 1;
    if (i + 1 < ktn) {
      stage(cur ^ 1, kt0 + i + 1);   // internal vmcnt(2) also drains cur's B
    } else {
      asm volatile("s_waitcnt vmcnt(0)" ::: "memory");
    }
    asm volatile("s_waitcnt lgkmcnt(0)" ::: "memory");  // A ds_writes visible
    __builtin_amdgcn_s_barrier();
    compute(cur);
    __builtin_amdgcn_s_barrier();
  }

  u16* op = outp + (size_t)bz * M * N;
#pragma unroll
  for (int ni = 0; ni < NF; ++ni) {
    const int n = n0 + wc * WN + ni * 16 + lr;
#pragma unroll
    for (int mi = 0; mi < MF; ++mi) {
#pragma unroll
      for (int r = 0; r < 4; ++r) {
        const int m = m0 + wr * WM + mi * 16 + lg * 4 + r;
        op[(size_t)m * N + n] = f2bf(acc[mi][ni][r]);
      }
    }
  }
}

// ---------------- flash attention: 128 q-rows/block, KV-split, fixed shift --
// (exact round-16/17 structure, unchanged)
template <int KSPLIT>
__global__ __launch_bounds__(256)
void k_attn(const u16* __restrict__ qk, const u16* __restrict__ vt,
            u16* __restrict__ Opart, float* __restrict__ lsum_out) {
  __shared__ u16 Klds[2][64 * 64];
  __shared__ u16 Vlds[2][64 * 64];
  const int tid = threadIdx.x;
  const int w = tid >> 6, l = tid & 63, lg = l >> 4, lr = l & 15;

  const int u = blockIdx.x + 16 * (blockIdx.y + NH * blockIdx.z);
  const int xcd = u & 7, g = u >> 3;
  const int h = 2 * xcd + (g / (16 * KSPLIT));
  const int rem = g % (16 * KSPLIT);
  const int sp = rem >> 4;
  const int qb2 = rem & 15;

  constexpr int NT = (SEQ / 64) / KSPLIT;
  const int kb0 = sp * NT;

  bf16x8 qfA[2], qfB[2];
  {
    const size_t qrowA = (size_t)(qb2 * 128 + w * 16 + lr) * 2048 + h * 64;
    qfA[0] = *reinterpret_cast<const bf16x8*>(&qk[qrowA + lg * 8]);
    qfA[1] = *reinterpret_cast<const bf16x8*>(&qk[qrowA + 32 + lg * 8]);
    const size_t qrowB = qrowA + (size_t)64 * 2048;
    qfB[0] = *reinterpret_cast<const bf16x8*>(&qk[qrowB + lg * 8]);
    qfB[1] = *reinterpret_cast<const bf16x8*>(&qk[qrowB + 32 + lg * 8]);
  }

  const int sr0 = w * 16 + (l >> 3);
  const int sc0 = ((l & 7) ^ (sr0 & 7)) * 8;
  const int sr1 = sr0 + 8;
  const int sc1 = ((l & 7) ^ (sr1 & 7)) * 8;
  const u16* kp0 = qk + 1024 + h * 64 + (size_t)(kb0 * 64 + sr0) * 2048 + sc0;
  const u16* kp1 = qk + 1024 + h * 64 + (size_t)(kb0 * 64 + sr1) * 2048 + sc1;
  const u16* vp0 = vt + (size_t)(h * 64 + sr0) * 2048 + kb0 * 64 + sc0;
  const u16* vp1 = vt + (size_t)(h * 64 + sr1) * 2048 + kb0 * 64 + sc1;

  auto stage = [&](int buf) {
    GLD_LDS16(kp0, &Klds[buf][(w * 16) * 64]);
    GLD_LDS16(kp1, &Klds[buf][(w * 16 + 8) * 64]);
    GLD_LDS16(vp0, &Vlds[buf][(w * 16) * 64]);
    GLD_LDS16(vp1, &Vlds[buf][(w * 16 + 8) * 64]);
    kp0 += (size_t)64 * 2048;
    kp1 += (size_t)64 * 2048;
    vp0 += 64;
    vp1 += 64;
  };

  auto kread = [&](int buf, int row, int kbyte) -> bf16x8 {
    const int off = row * 128 + (kbyte ^ ((row & 7) << 4));
    return *reinterpret_cast<const bf16x8*>(
        reinterpret_cast<const char*>(&Klds[buf][0]) + off);
  };

  f32x4 oaccA[4] = {}, oaccB[4] = {};
  f32x4 laccA = {}, laccB = {};
  const float SC = 0.18033688011112042f;  // log2(e)/8
  const s16x4 ONES = {(short)0x3F80, (short)0x3F80, (short)0x3F80, (short)0x3F80};

  stage(0);

  for (int t = 0; t < NT; ++t) {
    const int cur = t & 1;
    if (t + 1 < NT) {
      stage(cur ^ 1);
      asm volatile("s_waitcnt vmcnt(4)" ::: "memory");
    } else {
      asm volatile("s_waitcnt vmcnt(0)" ::: "memory");
    }
    __builtin_amdgcn_s_barrier();

    u32 pawA[4][2], pawB[4][2];
    __builtin_amdgcn_s_setprio(1);
#pragma unroll
    for (int nt = 0; nt < 4; ++nt) {
      bf16x8 kf0 = kread(cur, nt * 16 + lr, lg * 16);
      bf16x8 kf1 = kread(cur, nt * 16 + lr, 64 + lg * 16);
      f32x4 aA = {}, aB = {};
      aA = __builtin_amdgcn_mfma_f32_16x16x32_bf16(kf0, qfA[0], aA, 0, 0, 0);
      aA = __builtin_amdgcn_mfma_f32_16x16x32_bf16(kf1, qfA[1], aA, 0, 0, 0);
      aB = __builtin_amdgcn_mfma_f32_16x16x32_bf16(kf0, qfB[0], aB, 0, 0, 0);
      aB = __builtin_amdgcn_mfma_f32_16x16x32_bf16(kf1, qfB[1], aB, 0, 0, 0);
      float pA[4], pB[4];
#pragma unroll
      for (int r = 0; r < 4; ++r) {
        pA[r] = fast_exp2(aA[r] * SC);
        pB[r] = fast_exp2(aB[r] * SC);
      }
      pawA[nt][0] = packbf(pA[0], pA[1]);
      pawA[nt][1] = packbf(pA[2], pA[3]);
      pawB[nt][0] = packbf(pB[0], pB[1]);
      pawB[nt][1] = packbf(pB[2], pB[3]);
    }

#pragma unroll
    for (int nt = 0; nt < 4; ++nt) {
      union { u32 wd[2]; s16x4 v; } paA, paB;
      paA.wd[0] = pawA[nt][0]; paA.wd[1] = pawA[nt][1];
      paB.wd[0] = pawB[nt][0]; paB.wd[1] = pawB[nt][1];
      laccA = mfma16x16x16bf(paA.v, ONES, laccA);
      laccB = mfma16x16x16bf(paB.v, ONES, laccB);
#pragma unroll
      for (int nd = 0; nd < 4; ++nd) {
        const int row = nd * 16 + lr;
        const int off = row * 128 + ((nt * 32 + lg * 8) ^ ((row & 7) << 4));
        s16x4 vf = *reinterpret_cast<const s16x4*>(
            reinterpret_cast<const char*>(&Vlds[cur][0]) + off);
        oaccA[nd] = mfma16x16x16bf(paA.v, vf, oaccA[nd]);
        oaccB[nd] = mfma16x16x16bf(paB.v, vf, oaccB[nd]);
      }
    }
    __builtin_amdgcn_s_setprio(0);
    __builtin_amdgcn_s_barrier();
  }

  const size_t obase = (size_t)sp * SEQ * DM;
#pragma unroll
  for (int r = 0; r < 4; ++r) {
    const size_t qA = qb2 * 128 + w * 16 + lg * 4 + r;
    const size_t rowA = obase + qA * DM + h * 64;
    const size_t rowB = rowA + (size_t)64 * DM;
#pragma unroll
    for (int nd = 0; nd < 4; ++nd) {
      Opart[rowA + nd * 16 + lr] = f2bf(oaccA[nd][r]);
      Opart[rowB + nd * 16 + lr] = f2bf(oaccB[nd][r]);
    }
  }
  if (lr == 0) {
    const size_t lbase = ((size_t)sp * NH + h) * SEQ + qb2 * 128 + w * 16;
#pragma unroll
    for (int r = 0; r < 4; ++r) {
      lsum_out[lbase + lg * 4 + r] = laccA[r];
      lsum_out[lbase + 64 + lg * 4 + r] = laccB[r];
    }
  }
}

// ---------------- fused split-K combine + residual + bias + LayerNorm -------
__global__ __launch_bounds__(256)
void k_ln(const float* __restrict__ hin, const u16* __restrict__ pp,
          const float* __restrict__ bout, const float* __restrict__ gamma,
          const float* __restrict__ beta, float* __restrict__ out) {
  const int row = blockIdx.x, tid = threadIdx.x;
  const float4 hv = reinterpret_cast<const float4*>(hin + (size_t)row * DM)[tid];
  const ushort4 p0 = reinterpret_cast<const ushort4*>(pp + (size_t)row * DM)[tid];
  const ushort4 p1 = reinterpret_cast<const ushort4*>(pp + (size_t)(SEQ + row) * DM)[tid];
  const float4 bv = reinterpret_cast<const float4*>(bout)[tid];
  float4 v;
  v.x = hv.x + bf2f(p0.x) + bf2f(p1.x) + bv.x;
  v.y = hv.y + bf2f(p0.y) + bf2f(p1.y) + bv.y;
  v.z = hv.z + bf2f(p0.z) + bf2f(p1.z) + bv.z;
  v.w = hv.w + bf2f(p0.w) + bf2f(p1.w) + bv.w;
  float s = v.x + v.y + v.z + v.w;
  float q = v.x * v.x + v.y * v.y + v.z * v.z + v.w * v.w;
#pragma unroll
  for (int m = 1; m < 64; m <<= 1) { s += __shfl_xor(s, m); q += __shfl_xor(q, m); }
  __shared__ float sh[8];
  const int w = tid >> 6;
  if ((tid & 63) == 0) { sh[w] = s; sh[4 + w] = q; }
  __syncthreads();
  s = sh[0] + sh[1] + sh[2] + sh[3];
  q = sh[4] + sh[5] + sh[6] + sh[7];
  const float mu = s * (1.f / 1024.f);
  const float var = q * (1.f / 1024.f) - mu * mu;
  const float rstd = rsqrtf(var + LN_EPS);
  float4 g = reinterpret_cast<const float4*>(gamma)[tid];
  float4 b = reinterpret_cast<const float4*>(beta)[tid];
  float4 o;
  o.x = (v.x - mu) * rstd * g.x + b.x;
  o.y = (v.y - mu) * rstd * g.y + b.y;
  o.z = (v.z - mu) * rstd * g.z + b.z;
  o.w = (v.w - mu) * rstd * g.w + b.w;
  reinterpret_cast<float4*>(out + (size_t)row * DM)[tid] = o;
}

extern "C" void kernel_launch(void* const* d_in, const int* in_sizes, int n_in,
                              void* d_out, int out_size, void* d_ws, size_t ws_size,
                              hipStream_t stream) {
  const float* h     = (const float*)d_in[0];
  const float* Wqkv  = (const float*)d_in[1];
  const float* bqkv  = (const float*)d_in[2];
  const float* Wout  = (const float*)d_in[3];
  const float* bout  = (const float*)d_in[4];
  const float* gamma = (const float*)d_in[5];
  const float* beta  = (const float*)d_in[6];
  float* out = (float*)d_out;

  char* ws = (char*)d_ws;
  u16* h_bf      = (u16*)(ws);                              // 4 MB
  u16* Wqkv_bf   = (u16*)(ws + (size_t)4 * 1024 * 1024);    // 6 MB
  u16* Wout_bf   = (u16*)(ws + (size_t)10 * 1024 * 1024);   // 2 MB
  u16* qk_bf     = (u16*)(ws + (size_t)12 * 1024 * 1024);   // 8 MB
  u16* vt_bf     = (u16*)(ws + (size_t)20 * 1024 * 1024);   // 4 MB
  u16* Opart     = (u16*)(ws + (size_t)28 * 1024 * 1024);   // 16 MB (4 splits bf16)
  u16* Opp       = (u16*)(ws + (size_t)44 * 1024 * 1024);   // 8 MB (2 splits bf16)
  float* lsums   = (float*)(ws + (size_t)52 * 1024 * 1024); // 0.5 MB

  const int na = SEQ * DM / 4, nb = 3 * DM * DM / 4, nc = DM * DM / 4;
  k_f2bf3<<<(na + nb + nc + 255) / 256, 256, 0, stream>>>(
      h, h_bf, na, Wqkv, Wqkv_bf, nb, Wout, Wout_bf, nc);

  // QKV: 64x128 tiles, BK=64 swizzled + counted-vmcnt, 768 blocks = 3/CU
  k_gemm_bt<2, 64, 128, 3><<<dim3(24, 32), 256, 0, stream>>>(
      h_bf, Wqkv_bf, bqkv, qk_bf, vt_bf, SEQ, 3 * DM, DM);

  k_attn<4><<<dim3(16, 16, 4), 256, 0, stream>>>(qk_bf, vt_bf, Opart, lsums);

  // fused combine + out-proj: 64x64 tiles, split-K=2, 1024 blocks
  k_outproj<<<dim3(16, 32, 2), 256, 0, stream>>>(
      Opart, lsums, Wout_bf, Opp, SEQ, DM, DM);

  k_ln<<<SEQ, 256, 0, stream>>>(h, Opp, bout, gamma, beta, out);
}

// Round 19
// 83.230 us; speedup vs baseline: 1.1130x; 1.1130x over previous
//
#include <hip/hip_runtime.h>
#include <stdint.h>

#define SEQ 2048
#define DM 1024
#define NH 16
#define DH 64
#define LN_EPS 1e-5f

typedef __bf16 bf16x8 __attribute__((ext_vector_type(8)));
typedef float f32x4 __attribute__((ext_vector_type(4)));
typedef unsigned short u16;
typedef unsigned short u16x8 __attribute__((ext_vector_type(8)));
typedef unsigned int u32;
typedef short s16x4 __attribute__((ext_vector_type(4)));

__device__ __forceinline__ u16 f2bf(float f) {
  unsigned int u = __float_as_uint(f);
  unsigned int r = (u + 0x7fffu + ((u >> 16) & 1u)) >> 16;
  return (u16)r;
}

__device__ __forceinline__ float bf2f(u16 x) {
  return __uint_as_float(((u32)x) << 16);
}

__device__ __forceinline__ u32 packbf(float a, float b) {
  union { __bf16 h[2]; u32 u; } pw;
  pw.h[0] = (__bf16)a; pw.h[1] = (__bf16)b;
  return pw.u;
}

// raw v_exp_f32 (2^x). Args are bounded (|x|<40) so no OCML range fixup needed.
__device__ __forceinline__ float fast_exp2(float x) {
#if __has_builtin(__builtin_amdgcn_exp2f)
  return __builtin_amdgcn_exp2f(x);
#else
  float r;
  asm("v_exp_f32 %0, %1" : "=v"(r) : "v"(x));
  return r;
#endif
}

// 16x16x16 bf16 MFMA (2-reg A/B).
__device__ __forceinline__ f32x4 mfma16x16x16bf(s16x4 a, s16x4 b, f32x4 c) {
#if __has_builtin(__builtin_amdgcn_mfma_f32_16x16x16bf16_1k)
  return __builtin_amdgcn_mfma_f32_16x16x16bf16_1k(a, b, c, 0, 0, 0);
#else
  asm("v_mfma_f32_16x16x16_bf16 %0, %1, %2, %0" : "+v"(c) : "v"(a), "v"(b));
  return c;
#endif
}

#define GLD_LDS16(gp, lp) __builtin_amdgcn_global_load_lds( \
  (const __attribute__((address_space(1))) void*)(gp),      \
  (__attribute__((address_space(3))) void*)(lp), 16, 0, 0)

// ---------------- fused f32 -> bf16 convert (h, Wqkv, Wout in one launch) ----
__global__ __launch_bounds__(256)
void k_f2bf3(const float* __restrict__ a, u16* __restrict__ oa, int na,
             const float* __restrict__ b, u16* __restrict__ ob, int nb,
             const float* __restrict__ c, u16* __restrict__ oc, int nc) {
  int i = blockIdx.x * 256 + threadIdx.x;
  const float* src;
  u16* dst;
  if (i < na) { src = a; dst = oa; }
  else if (i < na + nb) { src = b; dst = ob; i -= na; }
  else if (i < na + nb + nc) { src = c; dst = oc; i -= na + nb; }
  else return;
  float4 v = reinterpret_cast<const float4*>(src)[i];
  ushort4 o;
  o.x = f2bf(v.x); o.y = f2bf(v.y); o.z = f2bf(v.z); o.w = f2bf(v.w);
  reinterpret_cast<ushort4*>(dst)[i] = o;
}

// ---------------- GEMM: C = A(bf16 MxK) * B(bf16 NxK)^T ----------------
// BK=64 k-step, XOR-swizzled LDS rows (round-14 proven) + T4 counted-vmcnt
// pipeline (round-16 proven in attn).
// EPI 2: QKV split: n<2048 -> outb[m][n]; n>=2048 -> outv[(n-2048)][m] (V^T).
// EPI 3: bf16 partials to outb[z][m][n] (no bias).
template <int EPI, int BM, int BN, int XCDW>
__global__ __launch_bounds__(256)
void k_gemm_bt(const u16* __restrict__ A, const u16* __restrict__ B,
               const float* __restrict__ bias,
               u16* __restrict__ outb, u16* __restrict__ outv,
               int M, int N, int K) {
  constexpr int MF = BM / 32, NF = BN / 32;
  constexpr int WM = BM / 2, WN = BN / 2;
  constexpr int NLOAD = BM / 32 + BN / 32;   // per-wave gld_lds per stage
  __shared__ u16 Alds[2][BM][64];
  __shared__ u16 Blds[2][BN][64];
  const int tid = threadIdx.x;
  const int w = tid >> 6, l = tid & 63, lg = l >> 4, lr = l & 15;
  const int wr = w >> 1, wc = w & 1;

  int bx = blockIdx.x, by = blockIdx.y, bz = blockIdx.z;
  if (XCDW > 0) {
    const int nx = gridDim.x, ny = gridDim.y;
    const int u = bx + nx * (by + ny * bz);
    const int xcd = u & 7, g = u >> 3;
    bx = xcd * XCDW + (g % XCDW);
    const int rem = g / XCDW;
    by = rem % ny;
    bz = rem / ny;
  }

  const int m0 = by * BM, n0 = bx * BN;
  const int KTall = K >> 6;
  const int ktn = KTall / gridDim.z;
  const int kt0 = bz * ktn;

  f32x4 acc[MF][NF] = {};

  const int srow = l >> 3;
  const int scol = ((l & 7) ^ (srow & 7)) * 8;
  auto stage = [&](int buf, int kt) {
    const int k0 = kt << 6;
#pragma unroll
    for (int p = 0; p < BM / 32; ++p) {
      const int rbase = (w * (BM / 32) + p) * 8;
      GLD_LDS16(A + (size_t)(m0 + rbase + srow) * K + k0 + scol, &Alds[buf][rbase][0]);
    }
#pragma unroll
    for (int p = 0; p < BN / 32; ++p) {
      const int rbase = (w * (BN / 32) + p) * 8;
      GLD_LDS16(B + (size_t)(n0 + rbase + srow) * K + k0 + scol, &Blds[buf][rbase][0]);
    }
  };

  auto aread = [&](int buf, int row, int kbyte) -> bf16x8 {
    const int off = row * 128 + (kbyte ^ ((row & 7) << 4));
    return *reinterpret_cast<const bf16x8*>(
        reinterpret_cast<const char*>(&Alds[buf][0][0]) + off);
  };
  auto bread = [&](int buf, int row, int kbyte) -> bf16x8 {
    const int off = row * 128 + (kbyte ^ ((row & 7) << 4));
    return *reinterpret_cast<const bf16x8*>(
        reinterpret_cast<const char*>(&Blds[buf][0][0]) + off);
  };

  auto compute = [&](int buf) {
#pragma unroll
    for (int kk = 0; kk < 2; ++kk) {
      bf16x8 af[MF], bfr[NF];
#pragma unroll
      for (int mi = 0; mi < MF; ++mi)
        af[mi] = aread(buf, wr * WM + mi * 16 + lr, kk * 64 + lg * 16);
#pragma unroll
      for (int ni = 0; ni < NF; ++ni)
        bfr[ni] = bread(buf, wc * WN + ni * 16 + lr, kk * 64 + lg * 16);
#pragma unroll
      for (int mi = 0; mi < MF; ++mi)
#pragma unroll
        for (int ni = 0; ni < NF; ++ni)
          acc[mi][ni] = __builtin_amdgcn_mfma_f32_16x16x32_bf16(af[mi], bfr[ni], acc[mi][ni], 0, 0, 0);
    }
  };

  stage(0, kt0);
  for (int i = 0; i < ktn; ++i) {
    const int cur = i & 1;
    if (i + 1 < ktn) {
      stage(cur ^ 1, kt0 + i + 1);
      if (NLOAD == 6)      asm volatile("s_waitcnt vmcnt(6)" ::: "memory");
      else if (NLOAD == 4) asm volatile("s_waitcnt vmcnt(4)" ::: "memory");
      else                 asm volatile("s_waitcnt vmcnt(0)" ::: "memory");
    } else {
      asm volatile("s_waitcnt vmcnt(0)" ::: "memory");
    }
    __builtin_amdgcn_s_barrier();   // buf cur full for all waves
    compute(cur);
    __builtin_amdgcn_s_barrier();   // all reads of buf cur done before reuse
  }

  if (EPI == 3) {
    u16* op = outb + (size_t)bz * M * N;
#pragma unroll
    for (int ni = 0; ni < NF; ++ni) {
      const int n = n0 + wc * WN + ni * 16 + lr;
#pragma unroll
      for (int mi = 0; mi < MF; ++mi) {
#pragma unroll
        for (int r = 0; r < 4; ++r) {
          const int m = m0 + wr * WM + mi * 16 + lg * 4 + r;
          op[(size_t)m * N + n] = f2bf(acc[mi][ni][r]);
        }
      }
    }
  } else {  // EPI == 2
    if (n0 < 2048) {
#pragma unroll
      for (int ni = 0; ni < NF; ++ni) {
        const int n = n0 + wc * WN + ni * 16 + lr;
        const float bn = bias[n];
#pragma unroll
        for (int mi = 0; mi < MF; ++mi) {
#pragma unroll
          for (int r = 0; r < 4; ++r) {
            const int m = m0 + wr * WM + mi * 16 + lg * 4 + r;
            outb[(size_t)m * 2048 + n] = f2bf(acc[mi][ni][r] + bn);
          }
        }
      }
    } else {
#pragma unroll
      for (int ni = 0; ni < NF; ++ni) {
        const int n = n0 + wc * WN + ni * 16 + lr;
        const float bn = bias[n];
#pragma unroll
        for (int mi = 0; mi < MF; ++mi) {
          const int mb = m0 + wr * WM + mi * 16 + lg * 4;
          ushort4 pk;
          pk.x = f2bf(acc[mi][ni][0] + bn);
          pk.y = f2bf(acc[mi][ni][1] + bn);
          pk.z = f2bf(acc[mi][ni][2] + bn);
          pk.w = f2bf(acc[mi][ni][3] + bn);
          *reinterpret_cast<ushort4*>(&outv[(size_t)(n - 2048) * M + mb]) = pk;
        }
      }
    }
  }
}

// ---------------- flash attention: 128 q-rows/block, KV-split, fixed shift --
// (exact round-16/17 structure, unchanged)
template <int KSPLIT>
__global__ __launch_bounds__(256)
void k_attn(const u16* __restrict__ qk, const u16* __restrict__ vt,
            u16* __restrict__ Opart, float* __restrict__ lsum_out) {
  __shared__ u16 Klds[2][64 * 64];
  __shared__ u16 Vlds[2][64 * 64];
  const int tid = threadIdx.x;
  const int w = tid >> 6, l = tid & 63, lg = l >> 4, lr = l & 15;

  // bijective remap of (qb2, h, sp): XCD k -> heads {2k, 2k+1}
  const int u = blockIdx.x + 16 * (blockIdx.y + NH * blockIdx.z);
  const int xcd = u & 7, g = u >> 3;
  const int h = 2 * xcd + (g / (16 * KSPLIT));
  const int rem = g % (16 * KSPLIT);
  const int sp = rem >> 4;
  const int qb2 = rem & 15;

  constexpr int NT = (SEQ / 64) / KSPLIT;
  const int kb0 = sp * NT;

  bf16x8 qfA[2], qfB[2];
  {
    const size_t qrowA = (size_t)(qb2 * 128 + w * 16 + lr) * 2048 + h * 64;
    qfA[0] = *reinterpret_cast<const bf16x8*>(&qk[qrowA + lg * 8]);
    qfA[1] = *reinterpret_cast<const bf16x8*>(&qk[qrowA + 32 + lg * 8]);
    const size_t qrowB = qrowA + (size_t)64 * 2048;
    qfB[0] = *reinterpret_cast<const bf16x8*>(&qk[qrowB + lg * 8]);
    qfB[1] = *reinterpret_cast<const bf16x8*>(&qk[qrowB + 32 + lg * 8]);
  }

  // running staging pointers (advance by constant strides per tile)
  const int sr0 = w * 16 + (l >> 3);
  const int sc0 = ((l & 7) ^ (sr0 & 7)) * 8;
  const int sr1 = sr0 + 8;
  const int sc1 = ((l & 7) ^ (sr1 & 7)) * 8;
  const u16* kp0 = qk + 1024 + h * 64 + (size_t)(kb0 * 64 + sr0) * 2048 + sc0;
  const u16* kp1 = qk + 1024 + h * 64 + (size_t)(kb0 * 64 + sr1) * 2048 + sc1;
  const u16* vp0 = vt + (size_t)(h * 64 + sr0) * 2048 + kb0 * 64 + sc0;
  const u16* vp1 = vt + (size_t)(h * 64 + sr1) * 2048 + kb0 * 64 + sc1;

  auto stage = [&](int buf) {
    GLD_LDS16(kp0, &Klds[buf][(w * 16) * 64]);
    GLD_LDS16(kp1, &Klds[buf][(w * 16 + 8) * 64]);
    GLD_LDS16(vp0, &Vlds[buf][(w * 16) * 64]);
    GLD_LDS16(vp1, &Vlds[buf][(w * 16 + 8) * 64]);
    kp0 += (size_t)64 * 2048;
    kp1 += (size_t)64 * 2048;
    vp0 += 64;
    vp1 += 64;
  };

  auto kread = [&](int buf, int row, int kbyte) -> bf16x8 {
    const int off = row * 128 + (kbyte ^ ((row & 7) << 4));
    return *reinterpret_cast<const bf16x8*>(
        reinterpret_cast<const char*>(&Klds[buf][0]) + off);
  };

  f32x4 oaccA[4] = {}, oaccB[4] = {};
  f32x4 laccA = {}, laccB = {};
  const float SC = 0.18033688011112042f;  // log2(e)/8
  const s16x4 ONES = {(short)0x3F80, (short)0x3F80, (short)0x3F80, (short)0x3F80};

  stage(0);

  for (int t = 0; t < NT; ++t) {
    const int cur = t & 1;
    if (t + 1 < NT) {
      stage(cur ^ 1);
      asm volatile("s_waitcnt vmcnt(4)" ::: "memory");
    } else {
      asm volatile("s_waitcnt vmcnt(0)" ::: "memory");
    }
    __builtin_amdgcn_s_barrier();

    u32 pawA[4][2], pawB[4][2];
    __builtin_amdgcn_s_setprio(1);
#pragma unroll
    for (int nt = 0; nt < 4; ++nt) {
      bf16x8 kf0 = kread(cur, nt * 16 + lr, lg * 16);
      bf16x8 kf1 = kread(cur, nt * 16 + lr, 64 + lg * 16);
      f32x4 aA = {}, aB = {};
      aA = __builtin_amdgcn_mfma_f32_16x16x32_bf16(kf0, qfA[0], aA, 0, 0, 0);
      aA = __builtin_amdgcn_mfma_f32_16x16x32_bf16(kf1, qfA[1], aA, 0, 0, 0);
      aB = __builtin_amdgcn_mfma_f32_16x16x32_bf16(kf0, qfB[0], aB, 0, 0, 0);
      aB = __builtin_amdgcn_mfma_f32_16x16x32_bf16(kf1, qfB[1], aB, 0, 0, 0);
      float pA[4], pB[4];
#pragma unroll
      for (int r = 0; r < 4; ++r) {
        pA[r] = fast_exp2(aA[r] * SC);
        pB[r] = fast_exp2(aB[r] * SC);
      }
      pawA[nt][0] = packbf(pA[0], pA[1]);
      pawA[nt][1] = packbf(pA[2], pA[3]);
      pawB[nt][0] = packbf(pB[0], pB[1]);
      pawB[nt][1] = packbf(pB[2], pB[3]);
    }

#pragma unroll
    for (int nt = 0; nt < 4; ++nt) {
      union { u32 wd[2]; s16x4 v; } paA, paB;
      paA.wd[0] = pawA[nt][0]; paA.wd[1] = pawA[nt][1];
      paB.wd[0] = pawB[nt][0]; paB.wd[1] = pawB[nt][1];
      laccA = mfma16x16x16bf(paA.v, ONES, laccA);
      laccB = mfma16x16x16bf(paB.v, ONES, laccB);
#pragma unroll
      for (int nd = 0; nd < 4; ++nd) {
        const int row = nd * 16 + lr;
        const int off = row * 128 + ((nt * 32 + lg * 8) ^ ((row & 7) << 4));
        s16x4 vf = *reinterpret_cast<const s16x4*>(
            reinterpret_cast<const char*>(&Vlds[cur][0]) + off);
        oaccA[nd] = mfma16x16x16bf(paA.v, vf, oaccA[nd]);
        oaccB[nd] = mfma16x16x16bf(paB.v, vf, oaccB[nd]);
      }
    }
    __builtin_amdgcn_s_setprio(0);
    __builtin_amdgcn_s_barrier();
  }

  const size_t obase = (size_t)sp * SEQ * DM;
#pragma unroll
  for (int r = 0; r < 4; ++r) {
    const size_t qA = qb2 * 128 + w * 16 + lg * 4 + r;
    const size_t rowA = obase + qA * DM + h * 64;
    const size_t rowB = rowA + (size_t)64 * DM;
#pragma unroll
    for (int nd = 0; nd < 4; ++nd) {
      Opart[rowA + nd * 16 + lr] = f2bf(oaccA[nd][r]);
      Opart[rowB + nd * 16 + lr] = f2bf(oaccB[nd][r]);
    }
  }
  if (lr == 0) {
    const size_t lbase = ((size_t)sp * NH + h) * SEQ + qb2 * 128 + w * 16;
#pragma unroll
    for (int r = 0; r < 4; ++r) {
      lsum_out[lbase + lg * 4 + r] = laccA[r];
      lsum_out[lbase + 64 + lg * 4 + r] = laccB[r];
    }
  }
}

// ---------------- combine KV-splits (same shift -> plain sum) ----------------
template <int KSPLIT>
__global__ __launch_bounds__(256)
void k_combine(const u16* __restrict__ Opart, const float* __restrict__ lsum,
               u16* __restrict__ attn_out) {
  const int row = blockIdx.x, tid = threadIdx.x;
  const int h = tid >> 4;
  float den = 0.f;
#pragma unroll
  for (int s = 0; s < KSPLIT; ++s)
    den += lsum[((size_t)s * NH + h) * SEQ + row];
  const float inv = 1.f / den;
  float o[4] = {0.f, 0.f, 0.f, 0.f};
#pragma unroll
  for (int s = 0; s < KSPLIT; ++s) {
    const ushort4 v = reinterpret_cast<const ushort4*>(
        Opart + ((size_t)s * SEQ + row) * DM)[tid];
    o[0] += bf2f(v.x); o[1] += bf2f(v.y);
    o[2] += bf2f(v.z); o[3] += bf2f(v.w);
  }
  ushort4 pk;
  pk.x = f2bf(o[0] * inv); pk.y = f2bf(o[1] * inv);
  pk.z = f2bf(o[2] * inv); pk.w = f2bf(o[3] * inv);
  reinterpret_cast<ushort4*>(attn_out + (size_t)row * DM)[tid] = pk;
}

// ---------------- fused split-K combine + residual + bias + LayerNorm -------
__global__ __launch_bounds__(256)
void k_ln(const float* __restrict__ hin, const u16* __restrict__ pp,
          const float* __restrict__ bout, const float* __restrict__ gamma,
          const float* __restrict__ beta, float* __restrict__ out) {
  const int row = blockIdx.x, tid = threadIdx.x;
  const float4 hv = reinterpret_cast<const float4*>(hin + (size_t)row * DM)[tid];
  const ushort4 p0 = reinterpret_cast<const ushort4*>(pp + (size_t)row * DM)[tid];
  const ushort4 p1 = reinterpret_cast<const ushort4*>(pp + (size_t)(SEQ + row) * DM)[tid];
  const float4 bv = reinterpret_cast<const float4*>(bout)[tid];
  float4 v;
  v.x = hv.x + bf2f(p0.x) + bf2f(p1.x) + bv.x;
  v.y = hv.y + bf2f(p0.y) + bf2f(p1.y) + bv.y;
  v.z = hv.z + bf2f(p0.z) + bf2f(p1.z) + bv.z;
  v.w = hv.w + bf2f(p0.w) + bf2f(p1.w) + bv.w;
  float s = v.x + v.y + v.z + v.w;
  float q = v.x * v.x + v.y * v.y + v.z * v.z + v.w * v.w;
#pragma unroll
  for (int m = 1; m < 64; m <<= 1) { s += __shfl_xor(s, m); q += __shfl_xor(q, m); }
  __shared__ float sh[8];
  const int w = tid >> 6;
  if ((tid & 63) == 0) { sh[w] = s; sh[4 + w] = q; }
  __syncthreads();
  s = sh[0] + sh[1] + sh[2] + sh[3];
  q = sh[4] + sh[5] + sh[6] + sh[7];
  const float mu = s * (1.f / 1024.f);
  const float var = q * (1.f / 1024.f) - mu * mu;
  const float rstd = rsqrtf(var + LN_EPS);
  float4 g = reinterpret_cast<const float4*>(gamma)[tid];
  float4 b = reinterpret_cast<const float4*>(beta)[tid];
  float4 o;
  o.x = (v.x - mu) * rstd * g.x + b.x;
  o.y = (v.y - mu) * rstd * g.y + b.y;
  o.z = (v.z - mu) * rstd * g.z + b.z;
  o.w = (v.w - mu) * rstd * g.w + b.w;
  reinterpret_cast<float4*>(out + (size_t)row * DM)[tid] = o;
}

extern "C" void kernel_launch(void* const* d_in, const int* in_sizes, int n_in,
                              void* d_out, int out_size, void* d_ws, size_t ws_size,
                              hipStream_t stream) {
  const float* h     = (const float*)d_in[0];
  const float* Wqkv  = (const float*)d_in[1];
  const float* bqkv  = (const float*)d_in[2];
  const float* Wout  = (const float*)d_in[3];
  const float* bout  = (const float*)d_in[4];
  const float* gamma = (const float*)d_in[5];
  const float* beta  = (const float*)d_in[6];
  float* out = (float*)d_out;

  char* ws = (char*)d_ws;
  u16* h_bf      = (u16*)(ws);                              // 4 MB
  u16* Wqkv_bf   = (u16*)(ws + (size_t)4 * 1024 * 1024);    // 6 MB
  u16* Wout_bf   = (u16*)(ws + (size_t)10 * 1024 * 1024);   // 2 MB
  u16* qk_bf     = (u16*)(ws + (size_t)12 * 1024 * 1024);   // 8 MB
  u16* vt_bf     = (u16*)(ws + (size_t)20 * 1024 * 1024);   // 4 MB
  u16* attn_bf   = (u16*)(ws + (size_t)24 * 1024 * 1024);   // 4 MB
  u16* Opart     = (u16*)(ws + (size_t)28 * 1024 * 1024);   // 16 MB (4 splits bf16)
  u16* Opp       = (u16*)(ws + (size_t)44 * 1024 * 1024);   // 8 MB (2 splits bf16)
  float* lsums   = (float*)(ws + (size_t)52 * 1024 * 1024); // 0.5 MB

  const int na = SEQ * DM / 4, nb = 3 * DM * DM / 4, nc = DM * DM / 4;
  k_f2bf3<<<(na + nb + nc + 255) / 256, 256, 0, stream>>>(
      h, h_bf, na, Wqkv, Wqkv_bf, nb, Wout, Wout_bf, nc);

  // QKV: 64x128 tiles, BK=64 swizzled + counted-vmcnt, 768 blocks = 3/CU
  k_gemm_bt<2, 64, 128, 3><<<dim3(24, 32), 256, 0, stream>>>(
      h_bf, Wqkv_bf, bqkv, qk_bf, vt_bf, SEQ, 3 * DM, DM);

  k_attn<4><<<dim3(16, 16, 4), 256, 0, stream>>>(qk_bf, vt_bf, Opart, lsums);
  k_combine<4><<<SEQ, 256, 0, stream>>>(Opart, lsums, attn_bf);

  // out-proj: 64x64 tiles, BK=64 swizzled + counted-vmcnt, split-K=2
  k_gemm_bt<3, 64, 64, 2><<<dim3(16, 32, 2), 256, 0, stream>>>(
      attn_bf, Wout_bf, nullptr, Opp, nullptr, SEQ, DM, DM);

  k_ln<<<SEQ, 256, 0, stream>>>(h, Opp, bout, gamma, beta, out);
}